// Round 9
// baseline (348.573 us; speedup 1.0000x reference)
//
#include <hip/hip_runtime.h>
#include <math.h>

// Problem constants
#define T_TOKENS 32768
#define DIM      2048
#define NEXP     256
#define NGROUP   8
#define GSIZE    32
#define TOPG     4
#define TOPK     8
#define SCALE    2.5
#define TAU      2e-5f     // rescue margin; 3-term bf16-split err sigma ~4e-7

// Main-pass tiling
#define BM  64
#define NSUB 64            // 32-k sub-steps
#define SC_STRIDE 257

#define RLIST_OFF 16                 // ints; ws[0] = counter
#define WPACK_OFF_BYTES (1 << 18)    // 256 KiB into d_ws

typedef __attribute__((ext_vector_type(8))) short bf16x8;
typedef __attribute__((ext_vector_type(8))) unsigned short u16x8;
typedef __attribute__((ext_vector_type(4))) float f32x4;

__device__ __forceinline__ unsigned short f2bf_rne(float f) {
    unsigned u = __float_as_uint(f);
    u += 0x7fffu + ((u >> 16) & 1u);
    return (unsigned short)(u >> 16);
}
__device__ __forceinline__ float bf2f(unsigned short h) {
    return __uint_as_float(((unsigned)h) << 16);
}

// ------------------------------------------------------------- pack W ----
// Wpack slot (s, n, h, lane) holds 8 bf16: W[e=16n+(lane&15)][k=32s+(lane>>4)*8+i]
__global__ void pack_w_kernel(const float* __restrict__ Wt,
                              unsigned short* __restrict__ wp,
                              int* __restrict__ ws) {
    if (blockIdx.x == 0 && threadIdx.x == 0) ws[0] = 0;   // rescue counter
    const int slot = blockIdx.x * 256 + threadIdx.x;      // 0..65535
    const int lane = slot & 63;
    const int n    = (slot >> 6) & 15;
    const int s    = slot >> 10;
    const int e    = n * 16 + (lane & 15);
    const int k0   = s * 32 + (lane >> 4) * 8;
    const float* src = Wt + (size_t)e * DIM + k0;
    const float4 v0 = *(const float4*)src;
    const float4 v1 = *(const float4*)(src + 4);
    const float a[8] = {v0.x, v0.y, v0.z, v0.w, v1.x, v1.y, v1.z, v1.w};
    union { unsigned short u[8]; u16x8 v; } uh, ul;
    #pragma unroll
    for (int i = 0; i < 8; ++i) {
        const unsigned short hb = f2bf_rne(a[i]);
        uh.u[i] = hb;
        ul.u[i] = f2bf_rne(a[i] - bf2f(hb));
    }
    const size_t base = ((size_t)(s * 16 + n) * 2) * 64 + lane;
    *(u16x8*)(wp + base * 8)        = uh.v;   // hi
    *(u16x8*)(wp + (base + 64) * 8) = ul.v;   // lo
}

// ---------------------------------------------------------------- main ----
// 256 threads = 4 independent waves, NO LDS / NO barriers in the K-loop.
// Wave w: all 4 M-tiles (64 tokens) x 4 N-tiles (experts 64w..64w+63).
// A-fragments loaded straight from global H (fp32) and cvt'd in-register;
// B-fragments from pre-packed wp (L2-resident).
__global__ __launch_bounds__(256, 2) void router_main(
    const float* __restrict__ H,
    const float* __restrict__ bias,
    const unsigned short* __restrict__ wp,
    float* __restrict__ out,
    int* __restrict__ ws)
{
    __shared__ float Sc[BM * SC_STRIDE];   // 65792 B (used only after K-loop)
    __shared__ float biasS[NEXP];

    const int tid  = threadIdx.x;
    const int lane = tid & 63;
    const int w    = tid >> 6;           // wave 0..3
    const int t0   = blockIdx.x * BM;

    biasS[tid] = bias[tid];

    f32x4 acc[4][4];   // [m][jj]
    #pragma unroll
    for (int m = 0; m < 4; ++m)
        #pragma unroll
        for (int jj = 0; jj < 4; ++jj)
            acc[m][jj] = (f32x4){0.f, 0.f, 0.f, 0.f};

    // A-frag addressing: frag m, this lane: row = t0+16m+(lane&15), col = 8*(lane>>4)
    const float* Abase = H + (size_t)(t0 + (lane & 15)) * DIM + (lane >> 4) * 8;

    auto loadA = [&](int s, float4 (&A)[4][2]) {
        #pragma unroll
        for (int m = 0; m < 4; ++m) {
            const float* p = Abase + (size_t)(16 * m) * DIM + s * 32;
            A[m][0] = *(const float4*)p;
            A[m][1] = *(const float4*)(p + 4);
        }
    };
    auto loadB = [&](int s, bf16x8 (&Bh)[4], bf16x8 (&Bl)[4]) {
        #pragma unroll
        for (int jj = 0; jj < 4; ++jj) {
            const size_t slot = ((size_t)(s * 16 + 4 * w + jj) * 2) * 64 + lane;
            Bh[jj] = *(const bf16x8*)(wp + slot * 8);
            Bl[jj] = *(const bf16x8*)(wp + (slot + 64) * 8);
        }
    };
    auto comp = [&](const float4 (&A)[4][2], bf16x8 (&Bh)[4], bf16x8 (&Bl)[4]) {
        #pragma unroll
        for (int m = 0; m < 4; ++m) {
            const float a[8] = {A[m][0].x, A[m][0].y, A[m][0].z, A[m][0].w,
                                A[m][1].x, A[m][1].y, A[m][1].z, A[m][1].w};
            union { unsigned short u[8]; u16x8 v; } uh, ul;
            #pragma unroll
            for (int i = 0; i < 8; ++i) {
                const unsigned short hb = f2bf_rne(a[i]);
                uh.u[i] = hb;
                ul.u[i] = f2bf_rne(a[i] - bf2f(hb));
            }
            const bf16x8 Ah = (bf16x8)uh.v;
            const bf16x8 Al = (bf16x8)ul.v;
            #pragma unroll
            for (int jj = 0; jj < 4; ++jj) {
                acc[m][jj] = __builtin_amdgcn_mfma_f32_16x16x32_bf16(Al, Bh[jj], acc[m][jj], 0, 0, 0);
                acc[m][jj] = __builtin_amdgcn_mfma_f32_16x16x32_bf16(Ah, Bl[jj], acc[m][jj], 0, 0, 0);
                acc[m][jj] = __builtin_amdgcn_mfma_f32_16x16x32_bf16(Ah, Bh[jj], acc[m][jj], 0, 0, 0);
            }
        }
    };

    float4 A0[4][2], A1[4][2];
    bf16x8 Bh0[4], Bl0[4], Bh1[4], Bl1[4];

    loadA(0, A0);
    loadB(0, Bh0, Bl0);

    for (int s = 0; s < NSUB; s += 2) {
        loadA(s + 1, A1);                 // prefetch next sub-step
        loadB(s + 1, Bh1, Bl1);
        comp(A0, Bh0, Bl0);
        if (s + 2 < NSUB) {
            loadA(s + 2, A0);
            loadB(s + 2, Bh0, Bl0);
        }
        comp(A1, Bh1, Bl1);
    }

    // ---- epilogue: biased sigmoid -> Sc (round-5-verified mapping) ----
    const int rbase = (lane >> 4) * 4;
    const int cc    = lane & 15;
    #pragma unroll
    for (int m = 0; m < 4; ++m)
        #pragma unroll
        for (int jj = 0; jj < 4; ++jj)
            #pragma unroll
            for (int r = 0; r < 4; ++r) {
                const int token  = 16 * m + rbase + r;
                const int expert = 64 * w + 16 * jj + cc;
                const float sg = 1.0f / (1.0f + expf(-acc[m][jj][r]));
                Sc[token * SC_STRIDE + expert] = sg + biasS[expert];
            }
    __syncthreads();

    // ---- routing (fp32) + margin check (round-4..7 proven) ----
    if (tid < BM) {
        float* row = &Sc[tid * SC_STRIDE];

        float gs[NGROUP];
        for (int g = 0; g < NGROUP; ++g) {
            const int base = g * GSIZE;
            float m1 = -3e38f, m2 = -3e38f;
            for (int j = 0; j < GSIZE; ++j) {
                const float v = row[base + j];
                if (v > m1) { m2 = m1; m1 = v; }
                else if (v > m2) { m2 = v; }
            }
            gs[g] = m1 + m2;
        }

        unsigned gsel = 0;
        float minSel = 3e38f, maxUn = -3e38f;
        #pragma unroll
        for (int g = 0; g < NGROUP; ++g) {
            int rank = 0;
            #pragma unroll
            for (int h = 0; h < NGROUP; ++h)
                rank += (gs[h] > gs[g]) || (gs[h] == gs[g] && h < g);
            if (rank < TOPG) { gsel |= 1u << g; minSel = fminf(minSel, gs[g]); }
            else             { maxUn = fmaxf(maxUn, gs[g]); }
        }
        float minMargin = minSel - maxUn;

        float wk[TOPK];
        int   ik[TOPK];
        float wsum = 0.0f;
        float prev = 3e38f;
        #pragma unroll
        for (int k = 0; k < TOPK + 1; ++k) {
            float bv = -3e38f;
            int   bi = 0;
            for (int g = 0; g < NGROUP; ++g) {
                if (!((gsel >> g) & 1u)) continue;
                const int base = g * GSIZE;
                for (int j = 0; j < GSIZE; ++j) {
                    const int e = base + j;
                    const float v = row[e];
                    if (v > bv) { bv = v; bi = e; }
                }
            }
            if (k > 0) minMargin = fminf(minMargin, prev - bv);
            prev = bv;
            if (k < TOPK) {
                const float wv = bv - biasS[bi];
                wk[k] = wv; ik[k] = bi; wsum += wv;
                row[bi] = -3e38f;
            }
        }

        const float norm = (float)SCALE / wsum;
        const size_t t = (size_t)(t0 + tid);
        float* oi = out + t * TOPK;
        float* ow = out + (size_t)T_TOKENS * TOPK + t * TOPK;
        #pragma unroll
        for (int k = 0; k < TOPK; ++k) {
            oi[k] = (float)ik[k];
            ow[k] = wk[k] * norm;
        }

        if (minMargin < TAU) {
            const int r = atomicAdd(ws, 1);
            ws[RLIST_OFF + r] = t0 + tid;
        }
    }
}

// -------------------------------------------------------------- rescue ----
// 2 tokens per block-iteration; threads = 64 experts x 4 k-chunks; exact fp64.
__global__ __launch_bounds__(256) void router_rescue(
    const float* __restrict__ H,
    const float* __restrict__ Wt,
    const float* __restrict__ bias,
    float* __restrict__ out,
    const int* __restrict__ ws)
{
    __shared__ float  Hs[2][DIM];          // 16 KiB
    __shared__ double Part[4][2][NEXP];    // 16 KiB
    __shared__ double Sd[2][NEXP];         //  4 KiB

    const int tid = threadIdx.x;
    const int nR  = ws[0];
    const int e0  = tid & 63;
    const int kc  = tid >> 6;              // 0..3

    for (int base = blockIdx.x * 2; base < nR; base += gridDim.x * 2) {
        const int nt = min(2, nR - base);
        __syncthreads();

        for (int j = 0; j < nt; ++j) {
            const int t = ws[RLIST_OFF + base + j];
            const float* hp = H + (size_t)t * DIM + tid * 8;
            const float4 a = *(const float4*)hp;
            const float4 b = *(const float4*)(hp + 4);
            float* d = &Hs[j][tid * 8];
            d[0] = a.x; d[1] = a.y; d[2] = a.z; d[3] = a.w;
            d[4] = b.x; d[5] = b.y; d[6] = b.z; d[7] = b.w;
        }
        __syncthreads();

        #pragma unroll
        for (int q = 0; q < 4; ++q) {
            const int e = e0 + 64 * q;
            const float* wr  = Wt + (size_t)e * DIM + kc * 512;
            const float* h0p = &Hs[0][kc * 512];
            const float* h1p = &Hs[1][kc * 512];
            double a00 = 0.0, a01 = 0.0, a10 = 0.0, a11 = 0.0;   // 4 indep chains
            for (int k = 0; k < 512; k += 8) {
                const float4 w0 = *(const float4*)(wr + k);
                const float4 w1 = *(const float4*)(wr + k + 4);
                a00 = fma((double)h0p[k + 0], (double)w0.x, a00);
                a00 = fma((double)h0p[k + 1], (double)w0.y, a00);
                a00 = fma((double)h0p[k + 2], (double)w0.z, a00);
                a00 = fma((double)h0p[k + 3], (double)w0.w, a00);
                a01 = fma((double)h0p[k + 4], (double)w1.x, a01);
                a01 = fma((double)h0p[k + 5], (double)w1.y, a01);
                a01 = fma((double)h0p[k + 6], (double)w1.z, a01);
                a01 = fma((double)h0p[k + 7], (double)w1.w, a01);
                a10 = fma((double)h1p[k + 0], (double)w0.x, a10);
                a10 = fma((double)h1p[k + 1], (double)w0.y, a10);
                a10 = fma((double)h1p[k + 2], (double)w0.z, a10);
                a10 = fma((double)h1p[k + 3], (double)w0.w, a10);
                a11 = fma((double)h1p[k + 4], (double)w1.x, a11);
                a11 = fma((double)h1p[k + 5], (double)w1.y, a11);
                a11 = fma((double)h1p[k + 6], (double)w1.z, a11);
                a11 = fma((double)h1p[k + 7], (double)w1.w, a11);
            }
            Part[kc][0][e] = a00 + a01;
            Part[kc][1][e] = a10 + a11;
        }
        __syncthreads();

        {   // reduce chunks (fixed order) + fp64 sigmoid + bias
            #pragma unroll
            for (int j = 0; j < 2; ++j) {
                const double sum = ((Part[0][j][tid] + Part[1][j][tid]) + Part[2][j][tid]) + Part[3][j][tid];
                Sd[j][tid] = 1.0 / (1.0 + exp(-sum)) + (double)bias[tid];
            }
        }
        __syncthreads();

        if (tid < nt) {
            double* row = Sd[tid];

            double gs[NGROUP];
            for (int g = 0; g < NGROUP; ++g) {
                const int b0 = g * GSIZE;
                double m1 = -1e300, m2 = -1e300;
                for (int j = 0; j < GSIZE; ++j) {
                    const double v = row[b0 + j];
                    if (v > m1) { m2 = m1; m1 = v; }
                    else if (v > m2) { m2 = v; }
                }
                gs[g] = m1 + m2;
            }

            unsigned gsel = 0;
            for (int g = 0; g < NGROUP; ++g) {
                int rank = 0;
                for (int h = 0; h < NGROUP; ++h)
                    rank += (gs[h] > gs[g]) || (gs[h] == gs[g] && h < g);
                if (rank < TOPG) gsel |= 1u << g;
            }

            double wk[TOPK];
            int    ik[TOPK];
            double wsum = 0.0;
            for (int k = 0; k < TOPK; ++k) {
                double bv = -1e300;
                int    bi = 0;
                for (int g = 0; g < NGROUP; ++g) {
                    if (!((gsel >> g) & 1u)) continue;
                    const int b0 = g * GSIZE;
                    for (int j = 0; j < GSIZE; ++j) {
                        const int e = b0 + j;
                        if (row[e] > bv) { bv = row[e]; bi = e; }
                    }
                }
                const double wv = bv - (double)bias[bi];
                wk[k] = wv; ik[k] = bi; wsum += wv;
                row[bi] = -1e300;
            }

            const double norm = SCALE / wsum;
            const int t = ws[RLIST_OFF + base + tid];
            float* oi = out + (size_t)t * TOPK;
            float* ow = out + (size_t)T_TOKENS * TOPK + (size_t)t * TOPK;
            for (int k = 0; k < TOPK; ++k) {
                oi[k] = (float)ik[k];
                ow[k] = (float)(wk[k] * norm);
            }
        }
    }
}

extern "C" void kernel_launch(void* const* d_in, const int* in_sizes, int n_in,
                              void* d_out, int out_size, void* d_ws, size_t ws_size,
                              hipStream_t stream) {
    const float* H    = (const float*)d_in[0];
    const float* Wt   = (const float*)d_in[1];
    const float* bias = (const float*)d_in[2];
    float* out = (float*)d_out;
    int*   ws  = (int*)d_ws;
    unsigned short* wp = (unsigned short*)((char*)d_ws + WPACK_OFF_BYTES);

    pack_w_kernel<<<256, 256, 0, stream>>>(Wt, wp, ws);
    router_main<<<T_TOKENS / BM, 256, 0, stream>>>(H, bias, wp, out, ws);
    router_rescue<<<256, 256, 0, stream>>>(H, Wt, bias, out, ws);
}

// Round 10
// 306.884 us; speedup vs baseline: 1.1358x; 1.1358x over previous
//
#include <hip/hip_runtime.h>
#include <math.h>

// Problem constants
#define T_TOKENS 32768
#define DIM      2048
#define NEXP     256
#define NGROUP   8
#define GSIZE    32
#define TOPG     4
#define TOPK     8
#define SCALE    2.5
#define TAU      2e-5f     // rescue margin; 3-term bf16-split err sigma ~2e-6

// Main-pass tiling
#define BM  32
#define NIT 32             // iterations of 64-k (2 sub-steps of 32)
#define SC_STRIDE 257      // 32*257*4 = 32896 B

#define RLIST_OFF 16                 // ints; ws[0] = counter
#define WPACK_OFF_BYTES (1 << 18)    // 256 KiB into d_ws

typedef __attribute__((ext_vector_type(8))) short bf16x8;
typedef __attribute__((ext_vector_type(8))) unsigned short u16x8;
typedef __attribute__((ext_vector_type(4))) float f32x4;

__device__ __forceinline__ unsigned short f2bf_rne(float f) {
    unsigned u = __float_as_uint(f);
    u += 0x7fffu + ((u >> 16) & 1u);
    return (unsigned short)(u >> 16);
}
__device__ __forceinline__ float bf2f(unsigned short h) {
    return __uint_as_float(((unsigned)h) << 16);
}

// ------------------------------------------------------------- pack W ----
// Wpack slot (s, n, h, lane) holds 8 bf16: W[e=16n+(lane&15)][k=32s+(lane>>4)*8+i]
__global__ void pack_w_kernel(const float* __restrict__ Wt,
                              unsigned short* __restrict__ wp,
                              int* __restrict__ ws) {
    if (blockIdx.x == 0 && threadIdx.x == 0) ws[0] = 0;   // rescue counter
    const int slot = blockIdx.x * 256 + threadIdx.x;      // 0..65535
    const int lane = slot & 63;
    const int n    = (slot >> 6) & 15;
    const int s    = slot >> 10;
    const int e    = n * 16 + (lane & 15);
    const int k0   = s * 32 + (lane >> 4) * 8;
    const float* src = Wt + (size_t)e * DIM + k0;
    const float4 v0 = *(const float4*)src;
    const float4 v1 = *(const float4*)(src + 4);
    const float a[8] = {v0.x, v0.y, v0.z, v0.w, v1.x, v1.y, v1.z, v1.w};
    union { unsigned short u[8]; u16x8 v; } uh, ul;
    #pragma unroll
    for (int i = 0; i < 8; ++i) {
        const unsigned short hb = f2bf_rne(a[i]);
        uh.u[i] = hb;
        ul.u[i] = f2bf_rne(a[i] - bf2f(hb));
    }
    const size_t base = ((size_t)(s * 16 + n) * 2) * 64 + lane;
    *(u16x8*)(wp + base * 8)        = uh.v;   // hi
    *(u16x8*)(wp + (base + 64) * 8) = ul.v;   // lo
}

// ---------------------------------------------------------------- main ----
// BM=32, 256 threads (4 waves), grid 1024 -> 4 independent blocks/CU
// (4 waves/SIMD in 4 separate sync domains). Wave w owns 2 M-tiles x 4
// N-tiles (frags 4w..4w+3). A staged in padded LDS (conflict-free), B from
// L2-resident packed wp. One barrier per 64-k iter.
__global__ __launch_bounds__(256, 4) void router_main(
    const float* __restrict__ H,
    const float* __restrict__ bias,
    const unsigned short* __restrict__ wp,
    float* __restrict__ out,
    int* __restrict__ ws)
{
    // union: Ahl dbuf (padded, 17408 B) / Sc (32896 B)
    __shared__ __align__(16) char smraw[BM * SC_STRIDE * 4];
    __shared__ float biasS[NEXP];

    // Ahl[buf][sub][h][m][slot][8]: slot = lane + (lane>>4)  (68 slots, padded)
    typedef unsigned short AhlT[2][2][2][68][8];     // per-buf: 8704 B
    AhlT* Ahl = reinterpret_cast<AhlT*>(smraw);
    float* Sc = reinterpret_cast<float*>(smraw);

    const int tid  = threadIdx.x;
    const int lane = tid & 63;
    const int w    = tid >> 6;           // wave 0..3
    const int t0   = blockIdx.x * BM;

    biasS[tid] = bias[tid];

    f32x4 acc[2][4];   // [m][jj]
    #pragma unroll
    for (int m = 0; m < 2; ++m)
        #pragma unroll
        for (int jj = 0; jj < 4; ++jj)
            acc[m][jj] = (f32x4){0.f, 0.f, 0.f, 0.f};

    // A staging mapping: 256 threads cover 32 rows x 8 k-octets (64 k per iter)
    const int arow = tid >> 3;           // 0..31
    const int koct = tid & 7;            // 0..7
    const int ssub = koct >> 2;          // 32-k half
    const int kq   = koct & 3;
    const int sm   = arow >> 4;          // m-plane 0/1
    const int r15  = arow & 15;
    const int wslot = kq * 16 + r15 + kq;    // lw + (lw>>4): padded, conflict-lite
    const float* Aptr = H + (size_t)(t0 + arow) * DIM + koct * 8;

    auto loadH = [&](int it, float4& x0, float4& x1) {
        const float* p = Aptr + (size_t)it * 64;
        x0 = *(const float4*)p;
        x1 = *(const float4*)(p + 4);
    };
    auto stageIter = [&](int b, const float4& x0, const float4& x1) {
        const float a[8] = {x0.x, x0.y, x0.z, x0.w, x1.x, x1.y, x1.z, x1.w};
        union { unsigned short u[8]; u16x8 v; } uh, ul;
        #pragma unroll
        for (int i = 0; i < 8; ++i) {
            const unsigned short hb = f2bf_rne(a[i]);
            uh.u[i] = hb;
            ul.u[i] = f2bf_rne(a[i] - bf2f(hb));
        }
        *(u16x8*)&Ahl[b][ssub][0][sm][wslot][0] = uh.v;
        *(u16x8*)&Ahl[b][ssub][1][sm][wslot][0] = ul.v;
    };
    const int rslot = lane + (lane >> 4);
    auto computeSub = [&](int b, int ss, int s) {
        bf16x8 Ah[2], Al[2];
        #pragma unroll
        for (int m = 0; m < 2; ++m) {
            Ah[m] = *(const bf16x8*)&Ahl[b][ss][0][m][rslot][0];
            Al[m] = *(const bf16x8*)&Ahl[b][ss][1][m][rslot][0];
        }
        bf16x8 Bh[4], Bl[4];
        #pragma unroll
        for (int jj = 0; jj < 4; ++jj) {
            const size_t slot = ((size_t)(s * 16 + 4 * w + jj) * 2) * 64 + lane;
            Bh[jj] = *(const bf16x8*)(wp + slot * 8);
            Bl[jj] = *(const bf16x8*)(wp + (slot + 64) * 8);
        }
        __builtin_amdgcn_s_setprio(1);
        #pragma unroll
        for (int m = 0; m < 2; ++m)
            #pragma unroll
            for (int jj = 0; jj < 4; ++jj) {
                acc[m][jj] = __builtin_amdgcn_mfma_f32_16x16x32_bf16(Al[m], Bh[jj], acc[m][jj], 0, 0, 0);
                acc[m][jj] = __builtin_amdgcn_mfma_f32_16x16x32_bf16(Ah[m], Bl[jj], acc[m][jj], 0, 0, 0);
                acc[m][jj] = __builtin_amdgcn_mfma_f32_16x16x32_bf16(Ah[m], Bh[jj], acc[m][jj], 0, 0, 0);
            }
        __builtin_amdgcn_s_setprio(0);
    };

    float4 hS0, hS1;

    // prologue: stage iter 0 into buf0; prefetch iter 1 into regs
    {
        float4 c0, c1;
        loadH(0, c0, c1);
        stageIter(0, c0, c1);
    }
    loadH(1, hS0, hS1);
    __syncthreads();

    for (int it = 0; it < NIT; ++it) {
        const int cur = it & 1;
        if (it + 1 < NIT) stageIter(cur ^ 1, hS0, hS1);   // stage iter+1
        if (it + 2 < NIT) loadH(it + 2, hS0, hS1);        // prefetch iter+2
        computeSub(cur, 0, 2 * it);
        computeSub(cur, 1, 2 * it + 1);
        __syncthreads();   // iter's reads + next-buf writes fenced together
    }

    // ---- epilogue: biased sigmoid -> Sc (aliases Ahl; K-loop barrier done) ----
    const int rbase = (lane >> 4) * 4;
    const int cc    = lane & 15;
    #pragma unroll
    for (int m = 0; m < 2; ++m)
        #pragma unroll
        for (int jj = 0; jj < 4; ++jj)
            #pragma unroll
            for (int r = 0; r < 4; ++r) {
                const int token  = 16 * m + rbase + r;
                const int expert = 16 * (4 * w + jj) + cc;
                const float sg = 1.0f / (1.0f + expf(-acc[m][jj][r]));
                Sc[token * SC_STRIDE + expert] = sg + biasS[expert];
            }
    __syncthreads();

    // ---- routing (fp32) + margin check (round-4..9 proven) ----
    if (tid < BM) {
        float* row = &Sc[tid * SC_STRIDE];

        float gs[NGROUP];
        for (int g = 0; g < NGROUP; ++g) {
            const int base = g * GSIZE;
            float m1 = -3e38f, m2 = -3e38f;
            for (int j = 0; j < GSIZE; ++j) {
                const float v = row[base + j];
                if (v > m1) { m2 = m1; m1 = v; }
                else if (v > m2) { m2 = v; }
            }
            gs[g] = m1 + m2;
        }

        unsigned gsel = 0;
        float minSel = 3e38f, maxUn = -3e38f;
        #pragma unroll
        for (int g = 0; g < NGROUP; ++g) {
            int rank = 0;
            #pragma unroll
            for (int h = 0; h < NGROUP; ++h)
                rank += (gs[h] > gs[g]) || (gs[h] == gs[g] && h < g);
            if (rank < TOPG) { gsel |= 1u << g; minSel = fminf(minSel, gs[g]); }
            else             { maxUn = fmaxf(maxUn, gs[g]); }
        }
        float minMargin = minSel - maxUn;

        float wk[TOPK];
        int   ik[TOPK];
        float wsum = 0.0f;
        float prev = 3e38f;
        #pragma unroll
        for (int k = 0; k < TOPK + 1; ++k) {
            float bv = -3e38f;
            int   bi = 0;
            for (int g = 0; g < NGROUP; ++g) {
                if (!((gsel >> g) & 1u)) continue;
                const int base = g * GSIZE;
                for (int j = 0; j < GSIZE; ++j) {
                    const int e = base + j;
                    const float v = row[e];
                    if (v > bv) { bv = v; bi = e; }
                }
            }
            if (k > 0) minMargin = fminf(minMargin, prev - bv);
            prev = bv;
            if (k < TOPK) {
                const float wv = bv - biasS[bi];
                wk[k] = wv; ik[k] = bi; wsum += wv;
                row[bi] = -3e38f;
            }
        }

        const float norm = (float)SCALE / wsum;
        const size_t t = (size_t)(t0 + tid);
        float* oi = out + t * TOPK;
        float* ow = out + (size_t)T_TOKENS * TOPK + t * TOPK;
        #pragma unroll
        for (int k = 0; k < TOPK; ++k) {
            oi[k] = (float)ik[k];
            ow[k] = wk[k] * norm;
        }

        if (minMargin < TAU) {
            const int r = atomicAdd(ws, 1);
            ws[RLIST_OFF + r] = t0 + tid;
        }
    }
}

// -------------------------------------------------------------- rescue ----
// 2 tokens per block-iteration; threads = 64 experts x 4 k-chunks; exact fp64.
__global__ __launch_bounds__(256) void router_rescue(
    const float* __restrict__ H,
    const float* __restrict__ Wt,
    const float* __restrict__ bias,
    float* __restrict__ out,
    const int* __restrict__ ws)
{
    __shared__ float  Hs[2][DIM];          // 16 KiB
    __shared__ double Part[4][2][NEXP];    // 16 KiB
    __shared__ double Sd[2][NEXP];         //  4 KiB

    const int tid = threadIdx.x;
    const int nR  = ws[0];
    const int e0  = tid & 63;
    const int kc  = tid >> 6;              // 0..3

    for (int base = blockIdx.x * 2; base < nR; base += gridDim.x * 2) {
        const int nt = min(2, nR - base);
        __syncthreads();

        for (int j = 0; j < nt; ++j) {
            const int t = ws[RLIST_OFF + base + j];
            const float* hp = H + (size_t)t * DIM + tid * 8;
            const float4 a = *(const float4*)hp;
            const float4 b = *(const float4*)(hp + 4);
            float* d = &Hs[j][tid * 8];
            d[0] = a.x; d[1] = a.y; d[2] = a.z; d[3] = a.w;
            d[4] = b.x; d[5] = b.y; d[6] = b.z; d[7] = b.w;
        }
        __syncthreads();

        #pragma unroll
        for (int q = 0; q < 4; ++q) {
            const int e = e0 + 64 * q;
            const float* wr  = Wt + (size_t)e * DIM + kc * 512;
            const float* h0p = &Hs[0][kc * 512];
            const float* h1p = &Hs[1][kc * 512];
            double a00 = 0.0, a01 = 0.0, a10 = 0.0, a11 = 0.0;   // 4 indep chains
            for (int k = 0; k < 512; k += 8) {
                const float4 w0 = *(const float4*)(wr + k);
                const float4 w1 = *(const float4*)(wr + k + 4);
                a00 = fma((double)h0p[k + 0], (double)w0.x, a00);
                a00 = fma((double)h0p[k + 1], (double)w0.y, a00);
                a00 = fma((double)h0p[k + 2], (double)w0.z, a00);
                a00 = fma((double)h0p[k + 3], (double)w0.w, a00);
                a01 = fma((double)h0p[k + 4], (double)w1.x, a01);
                a01 = fma((double)h0p[k + 5], (double)w1.y, a01);
                a01 = fma((double)h0p[k + 6], (double)w1.z, a01);
                a01 = fma((double)h0p[k + 7], (double)w1.w, a01);
                a10 = fma((double)h1p[k + 0], (double)w0.x, a10);
                a10 = fma((double)h1p[k + 1], (double)w0.y, a10);
                a10 = fma((double)h1p[k + 2], (double)w0.z, a10);
                a10 = fma((double)h1p[k + 3], (double)w0.w, a10);
                a11 = fma((double)h1p[k + 4], (double)w1.x, a11);
                a11 = fma((double)h1p[k + 5], (double)w1.y, a11);
                a11 = fma((double)h1p[k + 6], (double)w1.z, a11);
                a11 = fma((double)h1p[k + 7], (double)w1.w, a11);
            }
            Part[kc][0][e] = a00 + a01;
            Part[kc][1][e] = a10 + a11;
        }
        __syncthreads();

        {   // reduce chunks (fixed order) + fp64 sigmoid + bias
            #pragma unroll
            for (int j = 0; j < 2; ++j) {
                const double sum = ((Part[0][j][tid] + Part[1][j][tid]) + Part[2][j][tid]) + Part[3][j][tid];
                Sd[j][tid] = 1.0 / (1.0 + exp(-sum)) + (double)bias[tid];
            }
        }
        __syncthreads();

        if (tid < nt) {
            double* row = Sd[tid];

            double gs[NGROUP];
            for (int g = 0; g < NGROUP; ++g) {
                const int b0 = g * GSIZE;
                double m1 = -1e300, m2 = -1e300;
                for (int j = 0; j < GSIZE; ++j) {
                    const double v = row[b0 + j];
                    if (v > m1) { m2 = m1; m1 = v; }
                    else if (v > m2) { m2 = v; }
                }
                gs[g] = m1 + m2;
            }

            unsigned gsel = 0;
            for (int g = 0; g < NGROUP; ++g) {
                int rank = 0;
                for (int h = 0; h < NGROUP; ++h)
                    rank += (gs[h] > gs[g]) || (gs[h] == gs[g] && h < g);
                if (rank < TOPG) gsel |= 1u << g;
            }

            double wk[TOPK];
            int    ik[TOPK];
            double wsum = 0.0;
            for (int k = 0; k < TOPK; ++k) {
                double bv = -1e300;
                int    bi = 0;
                for (int g = 0; g < NGROUP; ++g) {
                    if (!((gsel >> g) & 1u)) continue;
                    const int b0 = g * GSIZE;
                    for (int j = 0; j < GSIZE; ++j) {
                        const int e = b0 + j;
                        if (row[e] > bv) { bv = row[e]; bi = e; }
                    }
                }
                const double wv = bv - (double)bias[bi];
                wk[k] = wv; ik[k] = bi; wsum += wv;
                row[bi] = -1e300;
            }

            const double norm = SCALE / wsum;
            const int t = ws[RLIST_OFF + base + tid];
            float* oi = out + (size_t)t * TOPK;
            float* ow = out + (size_t)T_TOKENS * TOPK + (size_t)t * TOPK;
            for (int k = 0; k < TOPK; ++k) {
                oi[k] = (float)ik[k];
                ow[k] = (float)(wk[k] * norm);
            }
        }
    }
}

extern "C" void kernel_launch(void* const* d_in, const int* in_sizes, int n_in,
                              void* d_out, int out_size, void* d_ws, size_t ws_size,
                              hipStream_t stream) {
    const float* H    = (const float*)d_in[0];
    const float* Wt   = (const float*)d_in[1];
    const float* bias = (const float*)d_in[2];
    float* out = (float*)d_out;
    int*   ws  = (int*)d_ws;
    unsigned short* wp = (unsigned short*)((char*)d_ws + WPACK_OFF_BYTES);

    pack_w_kernel<<<256, 256, 0, stream>>>(Wt, wp, ws);
    router_main<<<T_TOKENS / BM, 256, 0, stream>>>(H, bias, wp, out, ws);
    router_rescue<<<1024, 256, 0, stream>>>(H, Wt, bias, out, ws);
}

// Round 11
// 276.250 us; speedup vs baseline: 1.2618x; 1.1109x over previous
//
#include <hip/hip_runtime.h>
#include <math.h>

// Problem constants
#define T_TOKENS 32768
#define DIM      2048
#define NEXP     256
#define NGROUP   8
#define GSIZE    32
#define TOPG     4
#define TOPK     8
#define SCALE    2.5
#define TAU      2e-5f     // rescue margin; 3-term bf16-split err sigma ~4e-7

// Main-pass tiling
#define BM  64
#define NIT 32             // iterations of 64-k (2 sub-steps of 32)
#define SC_STRIDE 257

#define RLIST_OFF 16                 // ints; ws[0] = counter
#define WPACK_OFF_BYTES (1 << 18)    // 256 KiB into d_ws

typedef __attribute__((ext_vector_type(8))) short bf16x8;
typedef __attribute__((ext_vector_type(8))) unsigned short u16x8;
typedef __attribute__((ext_vector_type(4))) float f32x4;

__device__ __forceinline__ unsigned short f2bf_rne(float f) {
    unsigned u = __float_as_uint(f);
    u += 0x7fffu + ((u >> 16) & 1u);
    return (unsigned short)(u >> 16);
}
__device__ __forceinline__ float bf2f(unsigned short h) {
    return __uint_as_float(((unsigned)h) << 16);
}

// LDS-only barrier: orders ds ops across the workgroup but leaves global
// (vmcnt) loads in flight — __syncthreads would drain vmcnt(0) and expose
// the H/B prefetch latency every iteration (m97 stall).
__device__ __forceinline__ void lds_barrier() {
    __builtin_amdgcn_sched_barrier(0);
    asm volatile("s_waitcnt lgkmcnt(0)" ::: "memory");
    __builtin_amdgcn_s_barrier();
    __builtin_amdgcn_sched_barrier(0);
}

// ------------------------------------------------------------- pack W ----
// Wpack slot (s, n, h, lane) holds 8 bf16: W[e=16n+(lane&15)][k=32s+(lane>>4)*8+i]
__global__ void pack_w_kernel(const float* __restrict__ Wt,
                              unsigned short* __restrict__ wp,
                              int* __restrict__ ws) {
    if (blockIdx.x == 0 && threadIdx.x == 0) ws[0] = 0;   // rescue counter
    const int slot = blockIdx.x * 256 + threadIdx.x;      // 0..65535
    const int lane = slot & 63;
    const int n    = (slot >> 6) & 15;
    const int s    = slot >> 10;
    const int e    = n * 16 + (lane & 15);
    const int k0   = s * 32 + (lane >> 4) * 8;
    const float* src = Wt + (size_t)e * DIM + k0;
    const float4 v0 = *(const float4*)src;
    const float4 v1 = *(const float4*)(src + 4);
    const float a[8] = {v0.x, v0.y, v0.z, v0.w, v1.x, v1.y, v1.z, v1.w};
    union { unsigned short u[8]; u16x8 v; } uh, ul;
    #pragma unroll
    for (int i = 0; i < 8; ++i) {
        const unsigned short hb = f2bf_rne(a[i]);
        uh.u[i] = hb;
        ul.u[i] = f2bf_rne(a[i] - bf2f(hb));
    }
    const size_t base = ((size_t)(s * 16 + n) * 2) * 64 + lane;
    *(u16x8*)(wp + base * 8)        = uh.v;   // hi
    *(u16x8*)(wp + (base + 64) * 8) = ul.v;   // lo
}

// ---------------------------------------------------------------- main ----
// 512 threads = 8 waves; wave w owns 4 M-tiles x 2 N-tiles (2w, 2w+1).
// Grid 512 -> 2 blocks/CU -> 16 waves/CU. One LDS-only barrier per 64-k iter;
// global prefetches (H: HBM, B: L2) stay in flight across barriers.
__global__ __launch_bounds__(512, 4) void router_main(
    const float* __restrict__ H,
    const float* __restrict__ bias,
    const unsigned short* __restrict__ wp,
    float* __restrict__ out,
    int* __restrict__ ws)
{
    // union: Ahl dbuf (32 KiB) / Sc (65792 B)
    __shared__ __align__(16) char smraw[BM * SC_STRIDE * 4];
    __shared__ float biasS[NEXP];

    typedef unsigned short AhlBuf[2][2][4][64][8];   // [sub][h][m][lane][i]
    AhlBuf* Ahl = reinterpret_cast<AhlBuf*>(smraw);  // Ahl[buf]
    float*  Sc  = reinterpret_cast<float*>(smraw);

    const int tid  = threadIdx.x;
    const int lane = tid & 63;
    const int w    = tid >> 6;           // wave 0..7
    const int t0   = blockIdx.x * BM;

    if (tid < NEXP) biasS[tid] = bias[tid];

    f32x4 acc[4][2];   // [m][jj], expert tile = 2w+jj
    #pragma unroll
    for (int m = 0; m < 4; ++m)
        #pragma unroll
        for (int jj = 0; jj < 2; ++jj)
            acc[m][jj] = (f32x4){0.f, 0.f, 0.f, 0.f};

    // A staging mapping: 512 threads cover 64 rows x 8 k-octets (64 k per iter)
    const int arow = tid >> 3;           // 0..63
    const int koct = tid & 7;            // 0..7
    const int sub  = koct >> 2;          // which 32-k half
    const int kq   = koct & 3;
    const int am   = arow >> 4;
    const int lw   = (kq << 4) | (arow & 15);
    const float* Aptr = H + (size_t)(t0 + arow) * DIM + koct * 8;

    auto loadH = [&](int it, float4& x0, float4& x1) {
        const float* p = Aptr + (size_t)it * 64;
        x0 = *(const float4*)p;
        x1 = *(const float4*)(p + 4);
    };
    auto stageIter = [&](int b, const float4& x0, const float4& x1) {
        const float a[8] = {x0.x, x0.y, x0.z, x0.w, x1.x, x1.y, x1.z, x1.w};
        union { unsigned short u[8]; u16x8 v; } uh, ul;
        #pragma unroll
        for (int i = 0; i < 8; ++i) {
            const unsigned short hb = f2bf_rne(a[i]);
            uh.u[i] = hb;
            ul.u[i] = f2bf_rne(a[i] - bf2f(hb));
        }
        *(u16x8*)&Ahl[b][sub][0][am][lw][0] = uh.v;
        *(u16x8*)&Ahl[b][sub][1][am][lw][0] = ul.v;
    };
    auto loadB = [&](int s, bf16x8 (&Bh)[2], bf16x8 (&Bl)[2]) {
        #pragma unroll
        for (int jj = 0; jj < 2; ++jj) {
            const size_t slot = ((size_t)(s * 16 + 2 * w + jj) * 2) * 64 + lane;
            Bh[jj] = *(const bf16x8*)(wp + slot * 8);
            Bl[jj] = *(const bf16x8*)(wp + (slot + 64) * 8);
        }
    };
    auto computeSub = [&](int b, int ss, bf16x8 (&Bh)[2], bf16x8 (&Bl)[2]) {
        bf16x8 Ah[4], Al[4];
        #pragma unroll
        for (int m = 0; m < 4; ++m) {
            Ah[m] = *(const bf16x8*)&Ahl[b][ss][0][m][lane][0];
            Al[m] = *(const bf16x8*)&Ahl[b][ss][1][m][lane][0];
        }
        __builtin_amdgcn_s_setprio(1);
        #pragma unroll
        for (int m = 0; m < 4; ++m)
            #pragma unroll
            for (int jj = 0; jj < 2; ++jj) {
                acc[m][jj] = __builtin_amdgcn_mfma_f32_16x16x32_bf16(Al[m], Bh[jj], acc[m][jj], 0, 0, 0);
                acc[m][jj] = __builtin_amdgcn_mfma_f32_16x16x32_bf16(Ah[m], Bl[jj], acc[m][jj], 0, 0, 0);
                acc[m][jj] = __builtin_amdgcn_mfma_f32_16x16x32_bf16(Ah[m], Bh[jj], acc[m][jj], 0, 0, 0);
            }
        __builtin_amdgcn_s_setprio(0);
    };

    bf16x8 Ba_h[2], Ba_l[2], Bb_h[2], Bb_l[2];
    float4 hS0, hS1, hL0, hL1;

    // prologue: stage iter 0 into buf0, prefetch h(1), B(sub 0)
    {
        float4 c0, c1;
        loadH(0, c0, c1);
        stageIter(0, c0, c1);
    }
    loadH(1, hS0, hS1);
    loadB(0, Ba_h, Ba_l);
    lds_barrier();

    for (int it = 0; it < NIT; it += 2) {
        // ---- iter it: compute buf0 (subs 2it,2it+1); stage buf1 = A(it+1) ----
        loadH(min(it + 2, NIT - 1), hL0, hL1);
        stageIter(1, hS0, hS1);
        loadB(2 * it + 1, Bb_h, Bb_l);
        computeSub(0, 0, Ba_h, Ba_l);
        loadB(min(2 * it + 2, 2 * NIT - 1), Ba_h, Ba_l);
        computeSub(0, 1, Bb_h, Bb_l);
        lds_barrier();

        // ---- iter it+1: compute buf1; stage buf0 = A(it+2) ----
        loadH(min(it + 3, NIT - 1), hS0, hS1);
        if (it + 2 < NIT) stageIter(0, hL0, hL1);
        loadB(min(2 * it + 3, 2 * NIT - 1), Bb_h, Bb_l);
        computeSub(1, 0, Ba_h, Ba_l);
        loadB(min(2 * it + 4, 2 * NIT - 1), Ba_h, Ba_l);
        computeSub(1, 1, Bb_h, Bb_l);
        lds_barrier();
    }

    // ---- epilogue: biased sigmoid -> Sc ----
    const int rbase = (lane >> 4) * 4;
    const int cc    = lane & 15;
    #pragma unroll
    for (int m = 0; m < 4; ++m)
        #pragma unroll
        for (int jj = 0; jj < 2; ++jj)
            #pragma unroll
            for (int r = 0; r < 4; ++r) {
                const int token  = 16 * m + rbase + r;
                const int expert = 16 * (2 * w + jj) + cc;
                const float sg = 1.0f / (1.0f + expf(-acc[m][jj][r]));
                Sc[token * SC_STRIDE + expert] = sg + biasS[expert];
            }
    __syncthreads();

    // ---- routing (fp32) + margin check (round-4..7 proven) ----
    if (tid < BM) {
        float* row = &Sc[tid * SC_STRIDE];

        float gs[NGROUP];
        for (int g = 0; g < NGROUP; ++g) {
            const int base = g * GSIZE;
            float m1 = -3e38f, m2 = -3e38f;
            for (int j = 0; j < GSIZE; ++j) {
                const float v = row[base + j];
                if (v > m1) { m2 = m1; m1 = v; }
                else if (v > m2) { m2 = v; }
            }
            gs[g] = m1 + m2;
        }

        unsigned gsel = 0;
        float minSel = 3e38f, maxUn = -3e38f;
        #pragma unroll
        for (int g = 0; g < NGROUP; ++g) {
            int rank = 0;
            #pragma unroll
            for (int h = 0; h < NGROUP; ++h)
                rank += (gs[h] > gs[g]) || (gs[h] == gs[g] && h < g);
            if (rank < TOPG) { gsel |= 1u << g; minSel = fminf(minSel, gs[g]); }
            else             { maxUn = fmaxf(maxUn, gs[g]); }
        }
        float minMargin = minSel - maxUn;

        float wk[TOPK];
        int   ik[TOPK];
        float wsum = 0.0f;
        float prev = 3e38f;
        #pragma unroll
        for (int k = 0; k < TOPK + 1; ++k) {
            float bv = -3e38f;
            int   bi = 0;
            for (int g = 0; g < NGROUP; ++g) {
                if (!((gsel >> g) & 1u)) continue;
                const int base = g * GSIZE;
                for (int j = 0; j < GSIZE; ++j) {
                    const int e = base + j;
                    const float v = row[e];
                    if (v > bv) { bv = v; bi = e; }
                }
            }
            if (k > 0) minMargin = fminf(minMargin, prev - bv);
            prev = bv;
            if (k < TOPK) {
                const float wv = bv - biasS[bi];
                wk[k] = wv; ik[k] = bi; wsum += wv;
                row[bi] = -3e38f;
            }
        }

        const float norm = (float)SCALE / wsum;
        const size_t t = (size_t)(t0 + tid);
        float* oi = out + t * TOPK;
        float* ow = out + (size_t)T_TOKENS * TOPK + t * TOPK;
        #pragma unroll
        for (int k = 0; k < TOPK; ++k) {
            oi[k] = (float)ik[k];
            ow[k] = wk[k] * norm;
        }

        if (minMargin < TAU) {
            const int r = atomicAdd(ws, 1);
            ws[RLIST_OFF + r] = t0 + tid;
        }
    }
}

// -------------------------------------------------------------- rescue ----
// 2 tokens per block-iteration; threads = 64 experts x 4 k-chunks; exact fp64.
__global__ __launch_bounds__(256) void router_rescue(
    const float* __restrict__ H,
    const float* __restrict__ Wt,
    const float* __restrict__ bias,
    float* __restrict__ out,
    const int* __restrict__ ws)
{
    __shared__ float  Hs[2][DIM];          // 16 KiB
    __shared__ double Part[4][2][NEXP];    // 16 KiB
    __shared__ double Sd[2][NEXP];         //  4 KiB

    const int tid = threadIdx.x;
    const int nR  = ws[0];
    const int e0  = tid & 63;
    const int kc  = tid >> 6;              // 0..3

    for (int base = blockIdx.x * 2; base < nR; base += gridDim.x * 2) {
        const int nt = min(2, nR - base);
        __syncthreads();

        for (int j = 0; j < nt; ++j) {
            const int t = ws[RLIST_OFF + base + j];
            const float* hp = H + (size_t)t * DIM + tid * 8;
            const float4 a = *(const float4*)hp;
            const float4 b = *(const float4*)(hp + 4);
            float* d = &Hs[j][tid * 8];
            d[0] = a.x; d[1] = a.y; d[2] = a.z; d[3] = a.w;
            d[4] = b.x; d[5] = b.y; d[6] = b.z; d[7] = b.w;
        }
        __syncthreads();

        #pragma unroll
        for (int q = 0; q < 4; ++q) {
            const int e = e0 + 64 * q;
            const float* wr  = Wt + (size_t)e * DIM + kc * 512;
            const float* h0p = &Hs[0][kc * 512];
            const float* h1p = &Hs[1][kc * 512];
            double a00 = 0.0, a01 = 0.0, a10 = 0.0, a11 = 0.0;   // 4 indep chains
            for (int k = 0; k < 512; k += 8) {
                const float4 w0 = *(const float4*)(wr + k);
                const float4 w1 = *(const float4*)(wr + k + 4);
                a00 = fma((double)h0p[k + 0], (double)w0.x, a00);
                a00 = fma((double)h0p[k + 1], (double)w0.y, a00);
                a00 = fma((double)h0p[k + 2], (double)w0.z, a00);
                a00 = fma((double)h0p[k + 3], (double)w0.w, a00);
                a01 = fma((double)h0p[k + 4], (double)w1.x, a01);
                a01 = fma((double)h0p[k + 5], (double)w1.y, a01);
                a01 = fma((double)h0p[k + 6], (double)w1.z, a01);
                a01 = fma((double)h0p[k + 7], (double)w1.w, a01);
                a10 = fma((double)h1p[k + 0], (double)w0.x, a10);
                a10 = fma((double)h1p[k + 1], (double)w0.y, a10);
                a10 = fma((double)h1p[k + 2], (double)w0.z, a10);
                a10 = fma((double)h1p[k + 3], (double)w0.w, a10);
                a11 = fma((double)h1p[k + 4], (double)w1.x, a11);
                a11 = fma((double)h1p[k + 5], (double)w1.y, a11);
                a11 = fma((double)h1p[k + 6], (double)w1.z, a11);
                a11 = fma((double)h1p[k + 7], (double)w1.w, a11);
            }
            Part[kc][0][e] = a00 + a01;
            Part[kc][1][e] = a10 + a11;
        }
        __syncthreads();

        {   // reduce chunks (fixed order) + fp64 sigmoid + bias
            #pragma unroll
            for (int j = 0; j < 2; ++j) {
                const double sum = ((Part[0][j][tid] + Part[1][j][tid]) + Part[2][j][tid]) + Part[3][j][tid];
                Sd[j][tid] = 1.0 / (1.0 + exp(-sum)) + (double)bias[tid];
            }
        }
        __syncthreads();

        if (tid < nt) {
            double* row = Sd[tid];

            double gs[NGROUP];
            for (int g = 0; g < NGROUP; ++g) {
                const int b0 = g * GSIZE;
                double m1 = -1e300, m2 = -1e300;
                for (int j = 0; j < GSIZE; ++j) {
                    const double v = row[b0 + j];
                    if (v > m1) { m2 = m1; m1 = v; }
                    else if (v > m2) { m2 = v; }
                }
                gs[g] = m1 + m2;
            }

            unsigned gsel = 0;
            for (int g = 0; g < NGROUP; ++g) {
                int rank = 0;
                for (int h = 0; h < NGROUP; ++h)
                    rank += (gs[h] > gs[g]) || (gs[h] == gs[g] && h < g);
                if (rank < TOPG) gsel |= 1u << g;
            }

            double wk[TOPK];
            int    ik[TOPK];
            double wsum = 0.0;
            for (int k = 0; k < TOPK; ++k) {
                double bv = -1e300;
                int    bi = 0;
                for (int g = 0; g < NGROUP; ++g) {
                    if (!((gsel >> g) & 1u)) continue;
                    const int b0 = g * GSIZE;
                    for (int j = 0; j < GSIZE; ++j) {
                        const int e = b0 + j;
                        if (row[e] > bv) { bv = row[e]; bi = e; }
                    }
                }
                const double wv = bv - (double)bias[bi];
                wk[k] = wv; ik[k] = bi; wsum += wv;
                row[bi] = -1e300;
            }

            const double norm = SCALE / wsum;
            const int t = ws[RLIST_OFF + base + tid];
            float* oi = out + (size_t)t * TOPK;
            float* ow = out + (size_t)T_TOKENS * TOPK + (size_t)t * TOPK;
            for (int k = 0; k < TOPK; ++k) {
                oi[k] = (float)ik[k];
                ow[k] = (float)(wk[k] * norm);
            }
        }
    }
}

extern "C" void kernel_launch(void* const* d_in, const int* in_sizes, int n_in,
                              void* d_out, int out_size, void* d_ws, size_t ws_size,
                              hipStream_t stream) {
    const float* H    = (const float*)d_in[0];
    const float* Wt   = (const float*)d_in[1];
    const float* bias = (const float*)d_in[2];
    float* out = (float*)d_out;
    int*   ws  = (int*)d_ws;
    unsigned short* wp = (unsigned short*)((char*)d_ws + WPACK_OFF_BYTES);

    pack_w_kernel<<<256, 256, 0, stream>>>(Wt, wp, ws);
    router_main<<<T_TOKENS / BM, 512, 0, stream>>>(H, bias, wp, out, ws);
    router_rescue<<<512, 256, 0, stream>>>(H, Wt, bias, out, ws);
}